// Round 1
// baseline (236.257 us; speedup 1.0000x reference)
//
#include <hip/hip_runtime.h>

// CGP coupler: out[b, ro[k]] += x1[b, r1[k]] * x2[b, r2[k]] * cg[k]
// One block per batch row. x1/x2 row staged in LDS, output row accumulated in
// LDS via atomicAdd (ds_add_f32), then streamed out with float4 stores.

__global__ __launch_bounds__(256) void cgp_row_kernel(
    const float* __restrict__ x1,
    const float* __restrict__ x2,
    const float* __restrict__ cg,
    const int* __restrict__ r1,
    const int* __restrict__ r2,
    const int* __restrict__ ro,
    float* __restrict__ out,
    int in_dim, int out_dim, int K)
{
    extern __shared__ float lds[];
    float* x1s  = lds;                 // in_dim
    float* x2s  = lds + in_dim;        // in_dim
    float* outs = lds + 2 * in_dim;    // out_dim

    const int b    = blockIdx.x;
    const int tid  = threadIdx.x;
    const int nthr = blockDim.x;

    // ---- stage input rows (float4, in_dim assumed %4==0 which holds: 1024) ----
    {
        const float4* x1v = reinterpret_cast<const float4*>(x1 + (size_t)b * in_dim);
        const float4* x2v = reinterpret_cast<const float4*>(x2 + (size_t)b * in_dim);
        float4* x1sv = reinterpret_cast<float4*>(x1s);
        float4* x2sv = reinterpret_cast<float4*>(x2s);
        const int nv = in_dim >> 2;
        for (int i = tid; i < nv; i += nthr) {
            x1sv[i] = x1v[i];
            x2sv[i] = x2v[i];
        }
    }
    // ---- zero the output accumulator ----
    for (int j = tid; j < out_dim; j += nthr) outs[j] = 0.0f;
    __syncthreads();

    // ---- sparse bilinear scatter-accumulate ----
    // Entries come in runs of 32 with consecutive r1/r2/ro, so lane-linear k
    // gives coalesced index loads and (mostly) conflict-free LDS traffic.
    for (int k = tid; k < K; k += nthr) {
        const int i1 = r1[k];
        const int i2 = r2[k];
        const int io = ro[k];
        const float v = cg[k] * x1s[i1] * x2s[i2];
        atomicAdd(&outs[io], v);
    }
    __syncthreads();

    // ---- stream the accumulated row to global ----
    {
        float* orow = out + (size_t)b * out_dim;
        const int nv = out_dim >> 2;
        float4* og = reinterpret_cast<float4*>(orow);
        const float4* os = reinterpret_cast<const float4*>(outs);
        for (int j = tid; j < nv; j += nthr) og[j] = os[j];
        // scalar tail (out_dim % 4), defensive
        for (int j = (nv << 2) + tid; j < out_dim; j += nthr) orow[j] = outs[j];
    }
}

extern "C" void kernel_launch(void* const* d_in, const int* in_sizes, int n_in,
                              void* d_out, int out_size, void* d_ws, size_t ws_size,
                              hipStream_t stream)
{
    const float* x1 = (const float*)d_in[0];
    const float* x2 = (const float*)d_in[1];
    const float* cg = (const float*)d_in[2];
    const int*   r1 = (const int*)d_in[3];
    const int*   r2 = (const int*)d_in[4];
    const int*   ro = (const int*)d_in[5];
    float* out = (float*)d_out;

    const int in_dim = 1024;                 // sum(METADATA * n_irr), fixed by reference
    const int B      = in_sizes[0] / in_dim; // 2048
    const int out_dim = out_size / B;        // 8960
    const int K      = in_sizes[2];          // nnz entries

    const int block = 256;
    const size_t lds_bytes = (size_t)(2 * in_dim + out_dim) * sizeof(float);

    hipLaunchKernelGGL(cgp_row_kernel, dim3(B), dim3(block), lds_bytes, stream,
                       x1, x2, cg, r1, r2, ro, out, in_dim, out_dim, K);
}

// Round 3
// 77.915 us; speedup vs baseline: 3.0322x; 3.0322x over previous
//
#include <hip/hip_runtime.h>

// CGP coupler, segment-compressed block-ELL form.
//
// Structure (from the reference _build_coupler with METADATA all-32):
//   every run of 32 consecutive entries k has consecutive r1/r2/ro and a
//   CONSTANT cg; all bases are multiples of 32. So the op is
//     out[:, o:o+32] += cg_s * x1[:, a:a+32] * x2[:, b:b+32]
// over nseg = K/32 segments.
//
// Pipeline (all on stream, deterministic, graph-safe):
//   1. seg_extract : compress 32-entry runs to (a, b, ob, cg); histogram ob.
//   2. scan_kernel : exclusive scan of the output-block counts.
//   3. csr_fill    : stable (order-preserving) bucket fill via ballot/popc.
//   4. cgp_main    : 1 block/row; x1,x2 rows in LDS (8 KB); each 64-lane wave
//                    processes 2 segments at once (lane = half*32 + channel),
//                    register accumulation per output block, no atomics.

#define NOB_MAX 512   // out_dim/32 = 280 here; scan block = 512

__global__ void seg_extract(const int* __restrict__ r1, const int* __restrict__ r2,
                            const int* __restrict__ ro, const float* __restrict__ cg,
                            int nseg, int* __restrict__ segA, int* __restrict__ segB,
                            int* __restrict__ segOB, float* __restrict__ segCG,
                            int* __restrict__ cnt)
{
    int s = blockIdx.x * blockDim.x + threadIdx.x;
    if (s >= nseg) return;
    int k = s << 5;                 // first entry of the run (ns = 0)
    segA[s]  = r1[k];
    segB[s]  = r2[k];
    int ob   = ro[k] >> 5;          // output 32-block id
    segOB[s] = ob;
    segCG[s] = cg[k];
    atomicAdd(&cnt[ob], 1);
}

__global__ __launch_bounds__(512) void scan_kernel(const int* __restrict__ cnt,
                                                   int* __restrict__ off, int nob)
{
    __shared__ int buf[512];
    int t = threadIdx.x;
    buf[t] = (t < nob) ? cnt[t] : 0;
    __syncthreads();
    for (int d = 1; d < 512; d <<= 1) {
        int v = (t >= d) ? buf[t - d] : 0;
        __syncthreads();
        buf[t] += v;
        __syncthreads();
    }
    if (t < nob) off[t + 1] = buf[t];   // inclusive -> exclusive shifted
    if (t == 0) off[0] = 0;
}

__global__ void csr_fill(const int* __restrict__ segA, const int* __restrict__ segB,
                         const int* __restrict__ segOB, const float* __restrict__ segCG,
                         const int* __restrict__ off, int nseg, int nob,
                         int4* __restrict__ csr)
{
    int gtid = blockIdx.x * blockDim.x + threadIdx.x;
    int wave = gtid >> 6;
    int lane = gtid & 63;
    if (wave >= nob) return;
    int cursor = off[wave];
    for (int base = 0; base < nseg; base += 64) {
        int s = base + lane;
        bool m = (s < nseg) && (segOB[s] == wave);
        unsigned long long bal = __ballot(m);
        if (m) {
            int pos = cursor + __popcll(bal & ((1ull << lane) - 1ull));
            int4 d;
            d.x = segA[s];
            d.y = segB[s];
            d.z = __float_as_int(segCG[s]);
            d.w = 0;
            csr[pos] = d;
        }
        cursor += __popcll(bal);
    }
}

__global__ __launch_bounds__(256) void cgp_main(const float* __restrict__ x1,
                                                const float* __restrict__ x2,
                                                const int4* __restrict__ csr,
                                                const int* __restrict__ off,
                                                float* __restrict__ out,
                                                int in_dim, int out_dim, int nob)
{
    __shared__ float x1s[1024];
    __shared__ float x2s[1024];

    const int b   = blockIdx.x;
    const int tid = threadIdx.x;

    // stage input rows (1024 floats each = 256 float4; 256 threads -> 1 each)
    {
        const float4* p1 = reinterpret_cast<const float4*>(x1 + (size_t)b * in_dim);
        const float4* p2 = reinterpret_cast<const float4*>(x2 + (size_t)b * in_dim);
        float4* s1 = reinterpret_cast<float4*>(x1s);
        float4* s2 = reinterpret_cast<float4*>(x2s);
        const int nv = in_dim >> 2;
        for (int i = tid; i < nv; i += blockDim.x) {
            s1[i] = p1[i];
            s2[i] = p2[i];
        }
    }
    __syncthreads();

    const int wave = tid >> 6;      // 0..3
    const int lane = tid & 63;
    const int half = lane >> 5;     // which of the 2 concurrent segments
    const int t    = lane & 31;     // channel within the 32-block

    float* orow = out + (size_t)b * out_dim;

    for (int ob = wave; ob < nob; ob += 4) {
        const int s0  = off[ob];
        const int s1e = off[ob + 1];
        float acc0 = 0.0f, acc1 = 0.0f;
        int s = s0;
        // unrolled: 4 segments per iteration (2 per wave-half x 2 descriptors)
        for (; s + 4 <= s1e; s += 4) {
            int4 dA = csr[s + half];
            int4 dB = csr[s + 2 + half];
            acc0 += __int_as_float(dA.z) * x1s[dA.x + t] * x2s[dA.y + t];
            acc1 += __int_as_float(dB.z) * x1s[dB.x + t] * x2s[dB.y + t];
        }
        for (; s < s1e; s += 2) {
            int sm = s + half;
            if (sm < s1e) {
                int4 d = csr[sm];
                acc0 += __int_as_float(d.z) * x1s[d.x + t] * x2s[d.y + t];
            }
        }
        float acc = acc0 + acc1;
        acc += __shfl_xor(acc, 32);           // combine the two wave-halves
        if (half == 0) orow[(ob << 5) + t] = acc;
    }
}

extern "C" void kernel_launch(void* const* d_in, const int* in_sizes, int n_in,
                              void* d_out, int out_size, void* d_ws, size_t ws_size,
                              hipStream_t stream)
{
    const float* x1 = (const float*)d_in[0];
    const float* x2 = (const float*)d_in[1];
    const float* cg = (const float*)d_in[2];
    const int*   r1 = (const int*)d_in[3];
    const int*   r2 = (const int*)d_in[4];
    const int*   ro = (const int*)d_in[5];
    float* out = (float*)d_out;

    const int in_dim  = 1024;                  // fixed by METADATA
    const int B       = in_sizes[0] / in_dim;  // 2048
    const int out_dim = out_size / B;          // 8960
    const int K       = in_sizes[2];
    const int nseg    = K >> 5;                // all degs are 32
    const int nob     = out_dim >> 5;          // 280

    // ---- workspace layout (keep every array 16B aligned) ----
    auto align16 = [](size_t v) { return (v + 15) & ~(size_t)15; };
    char* ws = (char*)d_ws;
    int4*  csr   = (int4*)ws;   ws += align16((size_t)nseg * sizeof(int4));
    int*   segA  = (int*)ws;    ws += align16((size_t)nseg * sizeof(int));
    int*   segB  = (int*)ws;    ws += align16((size_t)nseg * sizeof(int));
    int*   segOB = (int*)ws;    ws += align16((size_t)nseg * sizeof(int));
    float* segCG = (float*)ws;  ws += align16((size_t)nseg * sizeof(float));
    int*   cnt   = (int*)ws;    ws += align16((size_t)NOB_MAX * sizeof(int));
    int*   off   = (int*)ws;

    hipMemsetAsync(cnt, 0, NOB_MAX * sizeof(int), stream);
    hipMemsetAsync(off, 0, (NOB_MAX + 1) * sizeof(int), stream);

    {
        int blk = 256, grd = (nseg + blk - 1) / blk;
        hipLaunchKernelGGL(seg_extract, dim3(grd), dim3(blk), 0, stream,
                           r1, r2, ro, cg, nseg, segA, segB, segOB, segCG, cnt);
    }
    hipLaunchKernelGGL(scan_kernel, dim3(1), dim3(512), 0, stream, cnt, off, nob);
    {
        int blk = 256, grd = (nob * 64 + blk - 1) / blk;
        hipLaunchKernelGGL(csr_fill, dim3(grd), dim3(blk), 0, stream,
                           segA, segB, segOB, segCG, off, nseg, nob, csr);
    }
    hipLaunchKernelGGL(cgp_main, dim3(B), dim3(256), 0, stream,
                       x1, x2, csr, off, out, in_dim, out_dim, nob);
}

// Round 4
// 64.522 us; speedup vs baseline: 3.6616x; 1.2076x over previous
//
#include <hip/hip_runtime.h>

// CGP coupler, scalar-descriptor block-ELL form.
//
// Structure (validated on-device in R3): entries come in runs of 32 with
// consecutive r1/r2/ro, constant cg, and 32-aligned bases. So the op is
//   out[:, o:o+32] += cg_s * x1[:, a:a+32] * x2[:, b:b+32]
// over nseg = K/32 segments, with a,b < 1024 (fit in u16).
//
// cgp_main: 1 block = 2 batch rows. Lane = half*32 + t, half = ROW index,
// t = channel. Descriptors are wave-uniform -> compiler scalarizes the
// 8-byte descriptor loads to s_load; inner loop is ~6 VALU+DS slots per
// segment covering both rows. Register accumulation per output block,
// no atomics, no output LDS.

#define NOB_MAX 512   // out_dim/32 = 280 here; scan block = 512

// ---- pass 1: compress runs to packed descriptors + histogram output blocks ----
__global__ void seg_extract(const int* __restrict__ r1, const int* __restrict__ r2,
                            const int* __restrict__ ro, const float* __restrict__ cg,
                            int nseg, unsigned int* __restrict__ segAB,
                            int* __restrict__ segOB, float* __restrict__ segCG,
                            int* __restrict__ cnt)
{
    int s = blockIdx.x * blockDim.x + threadIdx.x;
    if (s >= nseg) return;
    int k = s << 5;                         // first entry of the run
    unsigned int a = (unsigned int)r1[k];
    unsigned int b = (unsigned int)r2[k];
    segAB[s] = a | (b << 16);
    int ob = ro[k] >> 5;
    segOB[s] = ob;
    segCG[s] = cg[k];
    atomicAdd(&cnt[ob], 1);
}

// ---- pass 2: exclusive scan of per-output-block counts ----
__global__ __launch_bounds__(512) void scan_kernel(const int* __restrict__ cnt,
                                                   int* __restrict__ off, int nob)
{
    __shared__ int buf[512];
    int t = threadIdx.x;
    buf[t] = (t < nob) ? cnt[t] : 0;
    __syncthreads();
    for (int d = 1; d < 512; d <<= 1) {
        int v = (t >= d) ? buf[t - d] : 0;
        __syncthreads();
        buf[t] += v;
        __syncthreads();
    }
    if (t < nob) off[t + 1] = buf[t];
    if (t == 0) off[0] = 0;
}

// ---- pass 3: O(nseg) bucket fill (rank via atomic; order within ob is
//      arbitrary — fp reorder noise ~1e-5 << threshold) ----
__global__ void csr_fill(const unsigned int* __restrict__ segAB,
                         const int* __restrict__ segOB,
                         const float* __restrict__ segCG,
                         const int* __restrict__ off, int* __restrict__ rank,
                         int nseg, uint2* __restrict__ csr)
{
    int s = blockIdx.x * blockDim.x + threadIdx.x;
    if (s >= nseg) return;
    int ob = segOB[s];
    int pos = off[ob] + atomicAdd(&rank[ob], 1);
    uint2 d;
    d.x = segAB[s];
    d.y = __float_as_uint(segCG[s]);
    csr[pos] = d;
}

// ---- main: 2 rows per block, scalar descriptors, register accumulation ----
__global__ __launch_bounds__(256) void cgp_main(const float* __restrict__ x1,
                                                const float* __restrict__ x2,
                                                const uint2* __restrict__ csr,
                                                const int* __restrict__ off,
                                                float* __restrict__ out,
                                                int in_dim, int out_dim, int nob)
{
    __shared__ float x1s[2 * 1024];
    __shared__ float x2s[2 * 1024];

    const int b0  = blockIdx.x << 1;        // first of the 2 rows
    const int tid = threadIdx.x;

    // stage 2 contiguous rows of each input (8 KB each = 512 float4)
    {
        const float4* p1 = reinterpret_cast<const float4*>(x1 + (size_t)b0 * in_dim);
        const float4* p2 = reinterpret_cast<const float4*>(x2 + (size_t)b0 * in_dim);
        float4* s1 = reinterpret_cast<float4*>(x1s);
        float4* s2 = reinterpret_cast<float4*>(x2s);
        const int nv = (2 * in_dim) >> 2;   // 512
        for (int i = tid; i < nv; i += blockDim.x) {
            s1[i] = p1[i];
            s2[i] = p2[i];
        }
    }
    __syncthreads();

    const int wave = tid >> 6;              // 0..3
    const int lane = tid & 63;
    const int half = lane >> 5;             // ROW within the pair
    const int t    = lane & 31;             // channel within 32-block
    const int ldso = (half << 10) + t;      // half*1024 + t

    for (int ob = wave; ob < nob; ob += 4) {
        const int s0 = off[ob];
        const int s1 = off[ob + 1];
        float acc = 0.0f;
        #pragma unroll 4
        for (int s = s0; s < s1; ++s) {
            const uint2 d = csr[s];                      // wave-uniform -> s_load
            const int a = (int)(d.x & 0xFFFFu);
            const int b = (int)(d.x >> 16);
            const float c = __uint_as_float(d.y);
            acc = fmaf(c, x1s[ldso + a] * x2s[ldso + b], acc);
        }
        out[(size_t)(b0 + half) * out_dim + (ob << 5) + t] = acc;
    }
}

extern "C" void kernel_launch(void* const* d_in, const int* in_sizes, int n_in,
                              void* d_out, int out_size, void* d_ws, size_t ws_size,
                              hipStream_t stream)
{
    const float* x1 = (const float*)d_in[0];
    const float* x2 = (const float*)d_in[1];
    const float* cg = (const float*)d_in[2];
    const int*   r1 = (const int*)d_in[3];
    const int*   r2 = (const int*)d_in[4];
    const int*   ro = (const int*)d_in[5];
    float* out = (float*)d_out;

    const int in_dim  = 1024;                  // fixed by METADATA
    const int B       = in_sizes[0] / in_dim;  // 2048
    const int out_dim = out_size / B;          // 8960
    const int K       = in_sizes[2];
    const int nseg    = K >> 5;                // all degs are 32
    const int nob     = out_dim >> 5;          // 280

    // ---- workspace layout (16B-aligned carving) ----
    auto align16 = [](size_t v) { return (v + 15) & ~(size_t)15; };
    char* ws = (char*)d_ws;
    uint2*        csrD  = (uint2*)ws;        ws += align16((size_t)nseg * sizeof(uint2));
    unsigned int* segAB = (unsigned int*)ws; ws += align16((size_t)nseg * sizeof(unsigned int));
    int*          segOB = (int*)ws;          ws += align16((size_t)nseg * sizeof(int));
    float*        segCG = (float*)ws;        ws += align16((size_t)nseg * sizeof(float));
    int*          cnt   = (int*)ws;          ws += align16((size_t)NOB_MAX * sizeof(int));
    int*          rank  = (int*)ws;          ws += align16((size_t)NOB_MAX * sizeof(int));
    int*          off   = (int*)ws;

    // zero cnt + rank (contiguous regions, two small async memsets)
    hipMemsetAsync(cnt, 0, 2 * NOB_MAX * sizeof(int), stream);  // covers cnt AND rank

    {
        int blk = 256, grd = (nseg + blk - 1) / blk;
        hipLaunchKernelGGL(seg_extract, dim3(grd), dim3(blk), 0, stream,
                           r1, r2, ro, cg, nseg, segAB, segOB, segCG, cnt);
    }
    hipLaunchKernelGGL(scan_kernel, dim3(1), dim3(512), 0, stream, cnt, off, nob);
    {
        int blk = 256, grd = (nseg + blk - 1) / blk;
        hipLaunchKernelGGL(csr_fill, dim3(grd), dim3(blk), 0, stream,
                           segAB, segOB, segCG, off, rank, nseg, csrD);
    }
    hipLaunchKernelGGL(cgp_main, dim3(B >> 1), dim3(256), 0, stream,
                       x1, x2, csrD, off, out, in_dim, out_dim, nob);
}

// Round 5
// 48.934 us; speedup vs baseline: 4.8280x; 1.3185x over previous
//
#include <hip/hip_runtime.h>

// CGP coupler, L2-direct gather form.
//
// Structure (validated on-device R3/R4): entries come in runs of 32 with
// consecutive r1/r2/ro, constant cg, 32-aligned bases, a,b < 1024. So:
//   out[:, o:o+32] += cg_s * x1[:, a:a+32] * x2[:, b:b+32]
// over nseg = K/32 segments (~550), avg ~2 segments per output 32-block.
//
// cgp_main: block = 8 rows x 4 output-blocks; 256 threads = (row r, ch t).
// No LDS. Descriptors/offsets are wave-uniform -> scalar loads. Input
// slices read straight from L2 (XCD swizzle keeps each XCD's 256 rows =
// 2 MB resident in its 4 MiB L2). 4 independent ob chains per block for ILP.

#define NOB_MAX 512
#define ROWS 8
#define OBS 4

// ---- pass 1: histogram output blocks ----
__global__ void seg_count(const int* __restrict__ ro, int nseg,
                          int* __restrict__ cnt)
{
    int s = blockIdx.x * blockDim.x + threadIdx.x;
    if (s >= nseg) return;
    atomicAdd(&cnt[ro[s << 5] >> 5], 1);
}

// ---- pass 2: exclusive scan of per-output-block counts ----
__global__ __launch_bounds__(512) void scan_kernel(const int* __restrict__ cnt,
                                                   int* __restrict__ off, int nob)
{
    __shared__ int buf[512];
    int t = threadIdx.x;
    buf[t] = (t < nob) ? cnt[t] : 0;
    __syncthreads();
    for (int d = 1; d < 512; d <<= 1) {
        int v = (t >= d) ? buf[t - d] : 0;
        __syncthreads();
        buf[t] += v;
        __syncthreads();
    }
    if (t < nob) off[t + 1] = buf[t];
    if (t == 0) off[0] = 0;
}

// ---- pass 3: O(nseg) bucket fill (order within ob arbitrary; fp reorder
//      noise ~1e-5 << 0.29 threshold) ----
__global__ void csr_fill(const int* __restrict__ r1, const int* __restrict__ r2,
                         const int* __restrict__ ro, const float* __restrict__ cg,
                         const int* __restrict__ off, int* __restrict__ rank,
                         int nseg, uint2* __restrict__ csr)
{
    int s = blockIdx.x * blockDim.x + threadIdx.x;
    if (s >= nseg) return;
    int k = s << 5;
    int ob = ro[k] >> 5;
    int pos = off[ob] + atomicAdd(&rank[ob], 1);
    uint2 d;
    d.x = (unsigned int)r1[k] | ((unsigned int)r2[k] << 16);
    d.y = __float_as_uint(cg[k]);
    csr[pos] = d;
}

// ---- main ----
__global__ __launch_bounds__(256) void cgp_main(const float* __restrict__ x1,
                                                const float* __restrict__ x2,
                                                const uint2* __restrict__ csr,
                                                const int* __restrict__ off,
                                                float* __restrict__ out,
                                                int in_dim, int out_dim,
                                                int n_obg)
{
    // bijective XCD swizzle (gridDim.x % 8 == 0): each XCD gets a contiguous
    // chunk of swizzled ids; obg is the fast axis within a chunk, so one XCD
    // owns a contiguous band of rowtiles (2 MB of x1+x2 -> L2-resident).
    const int lin   = blockIdx.x;
    const int chunk = gridDim.x >> 3;
    const int sw    = (lin & 7) * chunk + (lin >> 3);
    const int obg     = sw % n_obg;
    const int rowtile = sw / n_obg;

    const int t = threadIdx.x & 31;          // channel within 32-block
    const int r = threadIdx.x >> 5;          // row within tile (0..7)
    const int row = rowtile * ROWS + r;

    const float* __restrict__ x1r = x1 + (size_t)row * in_dim + t;
    const float* __restrict__ x2r = x2 + (size_t)row * in_dim + t;
    float* __restrict__ outr = out + (size_t)row * out_dim + (obg * OBS) * 32 + t;

    const int ob0 = obg * OBS;

    #pragma unroll
    for (int i = 0; i < OBS; ++i) {
        const int s0 = off[ob0 + i];          // wave-uniform -> s_load
        const int s1 = off[ob0 + i + 1];
        float acc = 0.0f;
        for (int s = s0; s < s1; ++s) {
            const uint2 d = csr[s];           // wave-uniform -> s_load
            const int a = (int)(d.x & 0xFFFFu);
            const int b = (int)(d.x >> 16);
            acc = fmaf(__uint_as_float(d.y), x1r[a] * x2r[b], acc);
        }
        outr[i * 32] = acc;
    }
}

extern "C" void kernel_launch(void* const* d_in, const int* in_sizes, int n_in,
                              void* d_out, int out_size, void* d_ws, size_t ws_size,
                              hipStream_t stream)
{
    const float* x1 = (const float*)d_in[0];
    const float* x2 = (const float*)d_in[1];
    const float* cg = (const float*)d_in[2];
    const int*   r1 = (const int*)d_in[3];
    const int*   r2 = (const int*)d_in[4];
    const int*   ro = (const int*)d_in[5];
    float* out = (float*)d_out;

    const int in_dim  = 1024;                  // fixed by METADATA
    const int B       = in_sizes[0] / in_dim;  // 2048
    const int out_dim = out_size / B;          // 8960
    const int K       = in_sizes[2];
    const int nseg    = K >> 5;                // all degs are 32
    const int nob     = out_dim >> 5;          // 280
    const int n_obg   = nob / OBS;             // 70

    // ---- workspace layout (16B-aligned carving) ----
    auto align16 = [](size_t v) { return (v + 15) & ~(size_t)15; };
    char* ws = (char*)d_ws;
    uint2* csrD = (uint2*)ws;  ws += align16((size_t)nseg * sizeof(uint2));
    int*   cnt  = (int*)ws;    ws += align16((size_t)NOB_MAX * sizeof(int));
    int*   rank = (int*)ws;    ws += align16((size_t)NOB_MAX * sizeof(int));
    int*   off  = (int*)ws;

    hipMemsetAsync(cnt, 0, 2 * NOB_MAX * sizeof(int), stream);   // cnt AND rank

    {
        int blk = 256, grd = (nseg + blk - 1) / blk;
        hipLaunchKernelGGL(seg_count, dim3(grd), dim3(blk), 0, stream, ro, nseg, cnt);
    }
    hipLaunchKernelGGL(scan_kernel, dim3(1), dim3(512), 0, stream, cnt, off, nob);
    {
        int blk = 256, grd = (nseg + blk - 1) / blk;
        hipLaunchKernelGGL(csr_fill, dim3(grd), dim3(blk), 0, stream,
                           r1, r2, ro, cg, off, rank, nseg, csrD);
    }
    {
        const int nwg = (B / ROWS) * n_obg;    // 256 * 70 = 17920, % 8 == 0
        hipLaunchKernelGGL(cgp_main, dim3(nwg), dim3(256), 0, stream,
                           x1, x2, csrD, off, out, in_dim, out_dim, n_obg);
    }
}